// Round 8
// baseline (259.548 us; speedup 1.0000x reference)
//
#include <hip/hip_runtime.h>
#include <math.h>

#define BB 32
#define SS 2048
#define DD 512
#define AD 512

#define BM 128
#define BN 128
#define BK 64    // K elems per chunk; B row = 64 bf16 = 128 B = 8 granules

typedef __bf16 bf16;
typedef __attribute__((ext_vector_type(8))) __bf16 bf16x8;
typedef __attribute__((ext_vector_type(4))) __bf16 bf16x4;
typedef __attribute__((ext_vector_type(4))) float floatx4;

__device__ inline void async16(const void* g, void* l) {
    __builtin_amdgcn_global_load_lds(
        (const __attribute__((address_space(1))) unsigned int*)g,
        (__attribute__((address_space(3))) unsigned int*)l, 16, 0, 0);
}

// ---------------- K1: fused prep ----------------
// blocks [0, NCV)             : fp32->bf16 convert of W2 (1 MB only)
// blocks [NCV, NCV+64)        : mask dtype probe
// blocks [NCV+64, NCV+64+4096): w1q[b][a] = dot(query[b,:], W1[a,:])
#define NW8 (AD * DD / 8)
#define NCV (NW8 / 256)   // 128
__global__ void prep_kernel(const float* __restrict__ W2,
                            bf16* __restrict__ W2b,
                            const unsigned char* __restrict__ m8,
                            int* __restrict__ flag,
                            const float* __restrict__ query,
                            const float* __restrict__ W1,
                            float* __restrict__ w1q) {
    const int bid = blockIdx.x;
    if (bid < NCV) {
        int j = threadIdx.x + bid * 256;
        const float4* s4 = (const float4*)W2 + (size_t)j * 2;
        float4 x = s4[0], y = s4[1];
        bf16x8 o;
        o[0] = (bf16)x.x; o[1] = (bf16)x.y; o[2] = (bf16)x.z; o[3] = (bf16)x.w;
        o[4] = (bf16)y.x; o[5] = (bf16)y.y; o[6] = (bf16)y.z; o[7] = (bf16)y.w;
        *(bf16x8*)(W2b + (size_t)j * 8) = o;
    } else if (bid < NCV + 64) {
        int t = threadIdx.x + (bid - NCV) * 256;
        int any = 0;
        for (int i = t; i < BB * SS; i += 64 * 256)
            if ((i & 3) && m8[i]) any = 1;
        if (__any(any)) {
            if ((threadIdx.x & 63) == 0) atomicOr(flag, 1);
        }
    } else {
        int id = bid - NCV - 64;           // 0..4095
        int b = id >> 7;
        int a = (id & 127) * 4 + (threadIdx.x >> 6);
        int lane = threadIdx.x & 63;
        const float4* q4 = (const float4*)(query + (size_t)b * DD) + lane * 2;
        const float4* w4 = (const float4*)(W1 + (size_t)a * DD) + lane * 2;
        float4 qa = q4[0], qb = q4[1];
        float4 wa = w4[0], wb = w4[1];
        float acc = qa.x * wa.x + qa.y * wa.y + qa.z * wa.z + qa.w * wa.w
                  + qb.x * wb.x + qb.y * wb.y + qb.z * wb.z + qb.w * wb.w;
#pragma unroll
        for (int off = 32; off > 0; off >>= 1) acc += __shfl_down(acc, off);
        if (lane == 0) w1q[(size_t)b * AD + a] = acc;
    }
}

// ---------------- K2: A-in-registers MFMA GEMM + tanh/v epilogue ----------
// Wave tile = 32 m-rows x 128 n-cols (2 mi x 8 ni of 16x16x32). Each A-row
// belongs to ONE wave -> A-frags load global->VGPR directly in MFMA layout
// (lane(ml,kg): row w*32+mi*16+ml, bytes [kg*32, kg*32+32) of the 128B
// k-chunk half -- 16 rows x 128 contiguous B per instr, fully coalesced),
// cvt fp32->bf16 in regs. No LDS, no barrier on the A path.
// B = W2b bf16 via async16 into double-buffered LDS (2 x 16 KB), ONE
// barrier per chunk, 32 MFMA/wave/chunk. XOR granule swizzle g^(r&7).
// XCD-grouped 1-D grid; direct-store epilogue (4 partials per row).
__global__ __launch_bounds__(256, 3)
void gemm_scores_mfma(const float* __restrict__ keys,
                      const bf16* __restrict__ W2b,
                      const float* __restrict__ w1q,
                      const float* __restrict__ v,
                      float* __restrict__ partial) {
    __shared__ bf16 b_lds[2][BN * BK];   // 2 x 16 KB

    const int t    = threadIdx.x;
    const int lane = t & 63;
    const int w    = t >> 6;
    const int ml   = lane & 15;
    const int kg   = lane >> 4;

    // grid decode: lin -> (keys-tile kt, a_tile) with lin&7 == kt&7 (XCD)
    const int lin    = blockIdx.x;
    const int x8     = lin & 7;
    const int hi     = lin >> 3;
    const int a_tile = hi & 3;
    const int kt     = x8 + ((hi >> 2) << 3);   // 0..511
    const int b      = kt >> 4;
    const int s0     = (kt & 15) * BM;
    const int a0     = a_tile * BN;

    const float* Ablk = keys + ((size_t)b * SS + s0) * DD;
    const bf16*  Bblk = W2b + (size_t)a0 * DD;

    // this wave's two A row-bases (mi = 0,1)
    const float* arow0 = Ablk + (size_t)(w * 32 + ml) * DD;
    const float* arow1 = arow0 + 16 * DD;

    floatx4 acc[2][8];
#pragma unroll
    for (int mi = 0; mi < 2; ++mi)
#pragma unroll
        for (int ni = 0; ni < 8; ++ni)
            acc[mi][ni] = (floatx4)(0.f);

    // prologue: stage B chunk 0 into buf 0
#pragma unroll
    for (int i = 0; i < 4; ++i) {
        int g = t + 256 * i;
        int r = g >> 3, cc = g & 7, cs = cc ^ (r & 7);
        async16(Bblk + (size_t)r * DD + cs * 8, &b_lds[0][(256 * i + 64 * w) * 8]);
    }

    const int NCHUNK = DD / BK;   // 8
    for (int c = 0; c < NCHUNK; ++c) {
        const int cur = c & 1;
        __syncthreads();   // buf[cur] staged; prior reads of buf[!cur] done

        if (c + 1 < NCHUNK) {
            const int d0 = (c + 1) * BK;
#pragma unroll
            for (int i = 0; i < 4; ++i) {
                int g = t + 256 * i;
                int r = g >> 3, cc = g & 7, cs = cc ^ (r & 7);
                async16(Bblk + (size_t)r * DD + d0 + cs * 8,
                        &b_lds[!cur][(256 * i + 64 * w) * 8]);
            }
        }

        // A: global->reg, 8 float4 per lane (2 mi x 2 ks x 2 halves)
        const int ko = c * BK + kg * 8;
        float4 ga[2][2][2];
#pragma unroll
        for (int mi = 0; mi < 2; ++mi) {
            const float* ar = mi ? arow1 : arow0;
#pragma unroll
            for (int ks = 0; ks < 2; ++ks) {
                ga[mi][ks][0] = *(const float4*)(ar + ko + ks * 32);
                ga[mi][ks][1] = *(const float4*)(ar + ko + ks * 32 + 4);
            }
        }

#pragma unroll
        for (int ks = 0; ks < 2; ++ks) {
            bf16x8 af[2];
#pragma unroll
            for (int mi = 0; mi < 2; ++mi) {
                bf16x8 f;
                f[0] = (bf16)ga[mi][ks][0].x; f[1] = (bf16)ga[mi][ks][0].y;
                f[2] = (bf16)ga[mi][ks][0].z; f[3] = (bf16)ga[mi][ks][0].w;
                f[4] = (bf16)ga[mi][ks][1].x; f[5] = (bf16)ga[mi][ks][1].y;
                f[6] = (bf16)ga[mi][ks][1].z; f[7] = (bf16)ga[mi][ks][1].w;
                af[mi] = f;
            }
#pragma unroll
            for (int ni = 0; ni < 8; ++ni) {
                int R = ni * 16 + ml;
                int pos = (ks * 4 + kg) ^ (R & 7);
                bf16x8 bf = *(const bf16x8*)&b_lds[cur][R * BK + pos * 8];
#pragma unroll
                for (int mi = 0; mi < 2; ++mi)
                    acc[mi][ni] = __builtin_amdgcn_mfma_f32_16x16x32_bf16(
                        af[mi], bf, acc[mi][ni], 0, 0, 0);
            }
        }
    }

    // epilogue: tanh + v-weight over this wave's 128 a's per row; quad
    // shuffle-reduce (16 lanes) -> partial[(b,s)*4 + a_tile].
    float w1qa[8], va[8];
#pragma unroll
    for (int ni = 0; ni < 8; ++ni) {
        int a = a0 + ni * 16 + ml;
        w1qa[ni] = w1q[(size_t)b * AD + a];
        va[ni]   = v[a];
    }
#pragma unroll
    for (int mi = 0; mi < 2; ++mi) {
#pragma unroll
        for (int reg = 0; reg < 4; ++reg) {
            float p = 0.f;
#pragma unroll
            for (int ni = 0; ni < 8; ++ni) {
                float x = acc[mi][ni][reg] + w1qa[ni];
                float th = 1.f - 2.f / (1.f + __expf(2.f * x));
                p = fmaf(th, va[ni], p);
            }
            p += __shfl_xor(p, 1);
            p += __shfl_xor(p, 2);
            p += __shfl_xor(p, 4);
            p += __shfl_xor(p, 8);
            if (ml == 0) {
                int row = w * 32 + mi * 16 + kg * 4 + reg;
                partial[((size_t)b * SS + s0 + row) * 4 + a_tile] = p;
            }
        }
    }
}

// ---------------- K2-fallback (round-2 style, no ws converts) -------------
#define FBK 32
#define FLDK (FBK + 8)
__global__ __launch_bounds__(256, 2)
void gemm_scores_fallback(const float* __restrict__ keys,
                          const float* __restrict__ W2,
                          const float* __restrict__ w1q,
                          const float* __restrict__ v,
                          float* __restrict__ partial) {
    __shared__ bf16 a_lds[BM][FLDK];
    __shared__ bf16 b_lds[BN][FLDK];
    __shared__ float s_red[BM];

    const int t    = threadIdx.x;
    const int lane = t & 63;
    const int w    = t >> 6;
    const int ml   = lane & 15;
    const int kg   = lane >> 4;
    const int b    = blockIdx.z;
    const int s0   = blockIdx.x * BM;
    const int a0   = blockIdx.y * BN;
    const int m_off = (w & 1) * 64;
    const int n_off = (w >> 1) * 64;

    const float* Ablk = keys + ((size_t)b * SS + s0) * DD;
    const float* Bblk = W2 + (size_t)a0 * DD;

    if (t < BM) s_red[t] = 0.f;

    floatx4 acc[4][4];
#pragma unroll
    for (int mi = 0; mi < 4; ++mi)
#pragma unroll
        for (int ni = 0; ni < 4; ++ni)
            acc[mi][ni] = (floatx4)(0.f);

    float4 ga[4], gb[4];
#pragma unroll
    for (int i = 0; i < 4; ++i) {
        int idx = t + 256 * i;
        int r = idx >> 3, c = idx & 7;
        ga[i] = *(const float4*)(Ablk + (size_t)r * DD + c * 4);
        gb[i] = *(const float4*)(Bblk + (size_t)r * DD + c * 4);
    }

    for (int chunk = 0; chunk < DD / FBK; ++chunk) {
        __syncthreads();
#pragma unroll
        for (int i = 0; i < 4; ++i) {
            int idx = t + 256 * i;
            int r = idx >> 3, c = idx & 7;
            bf16x4 pa, pb;
            pa[0] = (bf16)ga[i].x; pa[1] = (bf16)ga[i].y;
            pa[2] = (bf16)ga[i].z; pa[3] = (bf16)ga[i].w;
            pb[0] = (bf16)gb[i].x; pb[1] = (bf16)gb[i].y;
            pb[2] = (bf16)gb[i].z; pb[3] = (bf16)gb[i].w;
            *(bf16x4*)&a_lds[r][c * 4] = pa;
            *(bf16x4*)&b_lds[r][c * 4] = pb;
        }
        __syncthreads();
        if (chunk < DD / FBK - 1) {
            int d0 = (chunk + 1) * FBK;
#pragma unroll
            for (int i = 0; i < 4; ++i) {
                int idx = t + 256 * i;
                int r = idx >> 3, c = idx & 7;
                ga[i] = *(const float4*)(Ablk + (size_t)r * DD + d0 + c * 4);
                gb[i] = *(const float4*)(Bblk + (size_t)r * DD + d0 + c * 4);
            }
        }
        bf16x8 af[4], bfr[4];
#pragma unroll
        for (int mi = 0; mi < 4; ++mi)
            af[mi] = *(const bf16x8*)&a_lds[m_off + mi * 16 + ml][kg * 8];
#pragma unroll
        for (int ni = 0; ni < 4; ++ni)
            bfr[ni] = *(const bf16x8*)&b_lds[n_off + ni * 16 + ml][kg * 8];
#pragma unroll
        for (int mi = 0; mi < 4; ++mi)
#pragma unroll
            for (int ni = 0; ni < 4; ++ni)
                acc[mi][ni] = __builtin_amdgcn_mfma_f32_16x16x32_bf16(
                    af[mi], bfr[ni], acc[mi][ni], 0, 0, 0);
    }

    float w1qa[4], va[4];
#pragma unroll
    for (int ni = 0; ni < 4; ++ni) {
        int a = a0 + n_off + ni * 16 + ml;
        w1qa[ni] = w1q[(size_t)b * AD + a];
        va[ni]   = v[a];
    }
#pragma unroll
    for (int mi = 0; mi < 4; ++mi) {
#pragma unroll
        for (int reg = 0; reg < 4; ++reg) {
            float p = 0.f;
#pragma unroll
            for (int ni = 0; ni < 4; ++ni) {
                float x = acc[mi][ni][reg] + w1qa[ni];
                float th = 1.f - 2.f / (1.f + __expf(2.f * x));
                p = fmaf(th, va[ni], p);
            }
            p += __shfl_xor(p, 1);
            p += __shfl_xor(p, 2);
            p += __shfl_xor(p, 4);
            p += __shfl_xor(p, 8);
            if (ml == 0)
                atomicAdd(&s_red[m_off + mi * 16 + kg * 4 + reg], p);
        }
    }
    __syncthreads();
    if (t < BM)
        partial[(((size_t)b * SS) + s0 + t) * 4 + blockIdx.y] = s_red[t];
}

// ---------------- K3: combine 4 partials + masked softmax over s ----------
__global__ void softmax_kernel(const float* __restrict__ partial,
                               const int* __restrict__ mask_i32,
                               const unsigned char* __restrict__ mask_u8,
                               const int* __restrict__ flag,
                               float* __restrict__ out) {
    const int b = blockIdx.x;
    const int t = threadIdx.x;
    __shared__ float rmax[4], rsum[4];
    const int wid = t >> 6, lane = t & 63;

    float sv[8]; int mv[8];
    const int bytes = (*flag != 0);
#pragma unroll
    for (int k = 0; k < 8; ++k) {
        int i = t + 256 * k;
        float4 p4 = *(const float4*)(partial + ((size_t)b * SS + i) * 4);
        sv[k] = (p4.x + p4.y) + (p4.z + p4.w);
        mv[k] = bytes ? (int)mask_u8[(size_t)b * SS + i]
                      : mask_i32[(size_t)b * SS + i];
    }

    float mx = -INFINITY;
#pragma unroll
    for (int k = 0; k < 8; ++k) mx = fmaxf(mx, mv[k] ? sv[k] : -INFINITY);
#pragma unroll
    for (int off = 32; off > 0; off >>= 1) mx = fmaxf(mx, __shfl_xor(mx, off));
    if (lane == 0) rmax[wid] = mx;
    __syncthreads();
    mx = fmaxf(fmaxf(rmax[0], rmax[1]), fmaxf(rmax[2], rmax[3]));

    float ev[8]; float sum = 0.f;
#pragma unroll
    for (int k = 0; k < 8; ++k) {
        ev[k] = mv[k] ? __expf(sv[k] - mx) : 0.f;
        sum += ev[k];
    }
#pragma unroll
    for (int off = 32; off > 0; off >>= 1) sum += __shfl_xor(sum, off);
    if (lane == 0) rsum[wid] = sum;
    __syncthreads();
    sum = (rsum[0] + rsum[1]) + (rsum[2] + rsum[3]);
    float inv = 1.f / sum;
#pragma unroll
    for (int k = 0; k < 8; ++k)
        out[(size_t)b * SS + t + 256 * k] = ev[k] * inv;
}

extern "C" void kernel_launch(void* const* d_in, const int* in_sizes, int n_in,
                              void* d_out, int out_size, void* d_ws, size_t ws_size,
                              hipStream_t stream) {
    const float* query = (const float*)d_in[0];
    const float* keys  = (const float*)d_in[1];
    const void*  mask  = d_in[2];
    const float* W1    = (const float*)d_in[3];
    const float* W2    = (const float*)d_in[4];
    const float* v     = (const float*)d_in[5];
    float* out = (float*)d_out;

    // ws layout (bytes): [flag 256][w1q 64K][partial 1M][W2b 0.5M]
    char* wsb = (char*)d_ws;
    int*   flag    = (int*)wsb;
    float* w1q     = (float*)(wsb + 256);
    float* partial = (float*)(wsb + 256 + 65536);
    bf16*  W2b     = (bf16*)(wsb + 256 + 65536 + 1048576);
    size_t need = 256 + 65536 + 1048576 + (size_t)AD * DD * 2;

    hipMemsetAsync(flag, 0, 4, stream);
    if (ws_size >= need) {
        prep_kernel<<<NCV + 64 + 4096, 256, 0, stream>>>(
            W2, W2b, (const unsigned char*)mask, flag, query, W1, w1q);
        gemm_scores_mfma<<<(SS / BM) * (AD / BN) * BB, 256, 0, stream>>>(
            keys, W2b, w1q, v, partial);
    } else {
        hipMemsetAsync(partial, 0, (size_t)BB * SS * 4 * 4, stream);
        prep_kernel<<<NCV + 64 + 4096, 256, 0, stream>>>(
            W2, W2b, (const unsigned char*)mask, flag, query, W1, w1q);
        gemm_scores_fallback<<<dim3(SS / BM, AD / BN, BB), 256, 0, stream>>>(
            keys, W2, w1q, v, partial);
    }
    softmax_kernel<<<BB, 256, 0, stream>>>(partial, (const int*)mask,
                                           (const unsigned char*)mask, flag, out);
}